// Round 5
// baseline (12961.501 us; speedup 1.0000x reference)
//
#include <hip/hip_runtime.h>

#define VV 100000
#define BB 2048
#define TT 200
#define GG 192   // 3*C
#define PP 514
#define RPB 8    // batch rows per block (mimn_rnn)

__device__ __forceinline__ float sigmf(float x) { return 1.0f / (1.0f + expf(-x)); }
__device__ __forceinline__ float softplusf(float x) {
    return fmaxf(x, 0.0f) + log1pf(expf(-fabsf(x)));
}
__device__ __forceinline__ float wred64(float x) {
#pragma unroll
    for (int m = 32; m >= 1; m >>= 1) x += __shfl_xor(x, m, 64);
    return x;
}

// ---------------- K0: per-vocab GI tables (bih folded into GI_item) -------------
__global__ __launch_bounds__(192) void build_tables(
    const float* __restrict__ emb,   // V x 64
    const float* __restrict__ Wih,   // 192 x 256
    const float* __restrict__ bih,   // 192
    float* __restrict__ GIi, float* __restrict__ GIc)  // V x 192 each
{
    __shared__ float sE[64 * 64];
    int tid = threadIdx.x;           // = n
    int v0 = blockIdx.x * 64;
    for (int i = tid; i < 64 * 64; i += 192) {
        int vv = i >> 6, k = i & 63;
        int gv = v0 + vv;
        sE[i] = (gv < VV) ? emb[(size_t)gv * 64 + k] : 0.0f;
    }
    __syncthreads();
    int n = tid;
    float bi = bih[n];
    {
        float4 w[16];
        const float4* wp = (const float4*)(Wih + n * 256);
#pragma unroll
        for (int q = 0; q < 16; ++q) w[q] = wp[q];
        for (int vv = 0; vv < 64; ++vv) {
            int gv = v0 + vv;
            if (gv >= VV) break;
            const float4* e = (const float4*)&sE[vv * 64];
            float acc = bi;
#pragma unroll
            for (int q = 0; q < 16; ++q) {
                float4 ee = e[q];
                acc += w[q].x * ee.x + w[q].y * ee.y + w[q].z * ee.z + w[q].w * ee.w;
            }
            GIi[(size_t)gv * GG + n] = acc;
        }
    }
    {
        float4 w[16];
        const float4* wp = (const float4*)(Wih + n * 256 + 64);
#pragma unroll
        for (int q = 0; q < 16; ++q) w[q] = wp[q];
        for (int vv = 0; vv < 64; ++vv) {
            int gv = v0 + vv;
            if (gv >= VV) break;
            const float4* e = (const float4*)&sE[vv * 64];
            float acc = 0.0f;
#pragma unroll
            for (int q = 0; q < 16; ++q) {
                float4 ee = e[q];
                acc += w[q].x * ee.x + w[q].y * ee.y + w[q].z * ee.z + w[q].w * ee.w;
            }
            GIc[(size_t)gv * GG + n] = acc;
        }
    }
}

// ---------------- K1: hist_sum + seq_len ----------------------------------------
__global__ __launch_bounds__(128) void hist_stats(
    const int* __restrict__ hist_item, const int* __restrict__ hist_cate,
    const float* __restrict__ mask, const float* __restrict__ emb,
    float* __restrict__ hist_sum, int* __restrict__ seqlen)
{
    int b = blockIdx.x, tid = threadIdx.x;
    const int* hidx = (tid < 64) ? hist_item : hist_cate;   // wave-uniform
    int j = tid & 63;
    float acc = 0.f;
    for (int t = 0; t < TT; ++t) {
        float m = mask[b * TT + t];
        int idx = hidx[b * TT + t];
        acc += m * emb[(size_t)idx * 64 + j];
    }
    hist_sum[(size_t)b * 128 + tid] = acc;
    if (tid < 64) {
        float s = 0.f;
        for (int t = tid; t < TT; t += 64) s += mask[b * TT + t];
        s = wred64(s);
        if (tid == 0) seqlen[b] = (int)(s + 0.5f);
    }
}

// ---------------- K2: recurrence, truly weight-stationary (128 VGPR) ------------
// Roles:
//   [0,512):    fused [read|h] @ [Wih_r|Whh] rows n<128 (r,z gates summed),
//               (n = tid&127, kq = tid>>7 of 48 cols), 12 float4 weights
//   [512,768):  i_n rows n=128+(u&63), kq=(u>>6) over read's 128 (32 each), 8 f4
//   [768,896):  h_n rows n=128+(u&63), kh=(u>>6) over h's 64 (32 each), 8 f4
//   [896,1024): gather prefetch threads (12 (r,n) pairs each, one step ahead)
//   all:        one Wp (n, k-half32) slice, 8 f4 (threads 1020-3: +1 leftover)
__global__ __launch_bounds__(1024, 4) void mimn_rnn(
    const int* __restrict__ hist_item, const int* __restrict__ hist_cate,
    const float* __restrict__ mask,
    const float* __restrict__ Wih,   // 192x256 (cols 128..255 = read part)
    const float* __restrict__ Whh,   // 192x64
    const float* __restrict__ bhh,   // 192
    const float* __restrict__ Wp,    // 514x64
    const float* __restrict__ bp,    // 514
    const float* __restrict__ Wo,    // 64x192
    const float* __restrict__ bo,    // 64
    const float* __restrict__ M0,    // 4x128
    const float* __restrict__ GIi, const float* __restrict__ GIc,
    const int* __restrict__ seqlen,
    float* __restrict__ last_out)    // B x 64
{
    // sU union:
    //  phase1/2: fused [kq*1024 + r*128 + n] 4096 | i_n 4096+[kq*512+r*64+n2] 2048
    //            | h_n 6144+[kh*512+r*64+n2] 1024 | gather 7168+[r*192+n] 1536
    //  phase3/4: p partials [kh*4112 + r*514 + n] 8224
    __shared__ float sU[8704];
    __shared__ float sM [RPB * 512];
    __shared__ float sRd[RPB * 128];
    __shared__ float sH [RPB * 64];
    __shared__ float sHn[RPB * 64];
    __shared__ float sBp[PP];
    __shared__ float sBhh[GG];
    __shared__ float sMask[RPB * TT];
    __shared__ int   sHI[RPB * TT];
    __shared__ int   sHC[RPB * TT];

    const int tid = threadIdx.x;
    const int b0 = blockIdx.x * RPB;

    // ---- init staged state ----
    for (int i = tid; i < RPB * 64; i += 1024) { sH[i] = 0.f; sHn[i] = 0.f; }
    for (int i = tid; i < RPB * 128; i += 1024) sRd[i] = 0.f;
    for (int i = tid; i < RPB * 512; i += 1024) sM[i] = M0[i & 511];
    for (int i = tid; i < PP; i += 1024) sBp[i] = bp[i];
    for (int i = tid; i < GG; i += 1024) sBhh[i] = bhh[i];
    for (int i = tid; i < RPB * TT; i += 1024) {
        int r = i / TT, tt = i - r * TT;
        sMask[i] = mask[(size_t)(b0 + r) * TT + tt];
        sHI[i]   = hist_item[(size_t)(b0 + r) * TT + tt];
        sHC[i]   = hist_cate[(size_t)(b0 + r) * TT + tt];
    }

    // ---- hoist weights (per-role) ----
    float4 W[12];
    int nA = 0, kqA = 0;
    if (tid < 512) {
        nA = tid & 127; kqA = tid >> 7;
#pragma unroll
        for (int j = 0; j < 12; ++j) {
            int col = kqA * 48 + j * 4;
            W[j] = (col < 128) ? *(const float4*)(Wih + nA * 256 + 128 + col)
                               : *(const float4*)(Whh + nA * 64 + (col - 128));
        }
    } else if (tid < 768) {
        int u = tid - 512; nA = u & 63; kqA = u >> 6;
#pragma unroll
        for (int j = 0; j < 8; ++j)
            W[j] = *(const float4*)(Wih + (128 + nA) * 256 + 128 + kqA * 32 + j * 4);
    } else if (tid < 896) {
        int u = tid - 768; nA = u & 63; kqA = u >> 6;
#pragma unroll
        for (int j = 0; j < 8; ++j)
            W[j] = *(const float4*)(Whh + (128 + nA) * 64 + kqA * 32 + j * 4);
    }
    // Wp slice (all threads)
    const int npP = (tid < 514) ? tid : tid - 514;
    const int khP = (tid < 514) ? 0 : 1;
    float4 Wq[8];
    {
        const float4* ws = (const float4*)(Wp + npP * 64 + khP * 32);
#pragma unroll
        for (int q = 0; q < 8; ++q) Wq[q] = ws[q];
    }
    const bool hasExtra = (tid >= 1020);        // leftover Wp rows 510..513, kh=1
    const int npE = 510 + (tid - 1020);
    float4 Wq2[8];
    if (hasExtra) {
        const float4* ws = (const float4*)(Wp + npE * 64 + 32);
#pragma unroll
        for (int q = 0; q < 8; ++q) Wq2[q] = ws[q];
    }
    int ts = 0;
    if (tid < 512) {
        int q = seqlen[b0 + (tid >> 6)] - 1;
        ts = q < 0 ? 0 : (q > TT - 1 ? TT - 1 : q);
    }
    __syncthreads();

    // ---- initial gather prefetch (t = 0) ----
    float2 P[12];
    if (tid >= 896) {
        int g = tid - 896;
#pragma unroll
        for (int s = 0; s < 12; ++s) {
            int idx = g + 128 * s; int r = idx / 192, n = idx - r * 192;
            P[s].x = GIi[(size_t)sHI[r * TT] * GG + n];
            P[s].y = GIc[(size_t)sHC[r * TT] * GG + n];
        }
    }

    for (int t = 0; t < TT; ++t) {
        // ---- phase 1: gate partials + gather commit & next-step prefetch ----
        if (tid < 512) {
            float acc[RPB];
#pragma unroll
            for (int r = 0; r < RPB; ++r) acc[r] = 0.f;
#pragma unroll
            for (int j = 0; j < 12; ++j) {
                int col = kqA * 48 + j * 4;      // wave-uniform branch
                float4 w = W[j];
                if (col < 128) {
#pragma unroll
                    for (int r = 0; r < RPB; ++r) {
                        float4 a = *(const float4*)&sRd[r * 128 + col];
                        acc[r] += w.x * a.x + w.y * a.y + w.z * a.z + w.w * a.w;
                    }
                } else {
#pragma unroll
                    for (int r = 0; r < RPB; ++r) {
                        float4 a = *(const float4*)&sH[r * 64 + (col - 128)];
                        acc[r] += w.x * a.x + w.y * a.y + w.z * a.z + w.w * a.w;
                    }
                }
            }
#pragma unroll
            for (int r = 0; r < RPB; ++r) sU[kqA * 1024 + r * 128 + nA] = acc[r];
        } else if (tid < 768) {
            float acc[RPB];
#pragma unroll
            for (int r = 0; r < RPB; ++r) acc[r] = 0.f;
#pragma unroll
            for (int j = 0; j < 8; ++j) {
                float4 w = W[j];
#pragma unroll
                for (int r = 0; r < RPB; ++r) {
                    float4 a = *(const float4*)&sRd[r * 128 + kqA * 32 + j * 4];
                    acc[r] += w.x * a.x + w.y * a.y + w.z * a.z + w.w * a.w;
                }
            }
#pragma unroll
            for (int r = 0; r < RPB; ++r) sU[4096 + kqA * 512 + r * 64 + nA] = acc[r];
        } else if (tid < 896) {
            float acc[RPB];
#pragma unroll
            for (int r = 0; r < RPB; ++r) acc[r] = 0.f;
#pragma unroll
            for (int j = 0; j < 8; ++j) {
                float4 w = W[j];
#pragma unroll
                for (int r = 0; r < RPB; ++r) {
                    float4 a = *(const float4*)&sH[r * 64 + kqA * 32 + j * 4];
                    acc[r] += w.x * a.x + w.y * a.y + w.z * a.z + w.w * a.w;
                }
            }
#pragma unroll
            for (int r = 0; r < RPB; ++r) sU[6144 + kqA * 512 + r * 64 + nA] = acc[r];
        } else {
            int g = tid - 896;
#pragma unroll
            for (int s = 0; s < 12; ++s) {
                int idx = g + 128 * s; int r = idx / 192, n = idx - r * 192;
                sU[7168 + r * 192 + n] = P[s].x + P[s].y;
            }
            int tn = (t + 1 < TT) ? t + 1 : TT - 1;
#pragma unroll
            for (int s = 0; s < 12; ++s) {
                int idx = g + 128 * s; int r = idx / 192, n = idx - r * 192;
                P[s].x = GIi[(size_t)sHI[r * TT + tn] * GG + n];
                P[s].y = GIc[(size_t)sHC[r * TT + tn] * GG + n];
            }
        }
        __syncthreads();
        // ---- phase 2: GRU gates; commit h ----
        if (tid < 512) {
            int r = tid >> 6, lane = tid & 63;
            int cb = r * 128 + lane;
            float g_r = sU[cb] + sU[1024 + cb] + sU[2048 + cb] + sU[3072 + cb]
                      + sU[7168 + r * 192 + lane] + sBhh[lane];
            float g_z = sU[64 + cb] + sU[1024 + 64 + cb] + sU[2048 + 64 + cb] + sU[3072 + 64 + cb]
                      + sU[7168 + r * 192 + 64 + lane] + sBhh[64 + lane];
            int ib = r * 64 + lane;
            float i_n = sU[4096 + ib] + sU[4096 + 512 + ib] + sU[4096 + 1024 + ib] + sU[4096 + 1536 + ib]
                      + sU[7168 + r * 192 + 128 + lane];
            float h_n = sU[6144 + ib] + sU[6144 + 512 + ib] + sBhh[128 + lane];
            float rg = sigmf(g_r);
            float zg = sigmf(g_z);
            float ng = tanhf(i_n + rg * h_n);
            float h_old = sH[r * 64 + lane];
            float hn = (1.f - zg) * ng + zg * h_old;
            float mt = sMask[r * TT + t];
            sHn[r * 64 + lane] = hn;
            sH[r * 64 + lane] = (mt > 0.f) ? hn : h_old;
        }
        __syncthreads();
        // ---- phase 3: p partials = h_new @ Wp^T ----
        {
            float acc[RPB];
#pragma unroll
            for (int r = 0; r < RPB; ++r) acc[r] = 0.f;
#pragma unroll
            for (int q = 0; q < 8; ++q) {
                float4 w = Wq[q];
#pragma unroll
                for (int r = 0; r < RPB; ++r) {
                    float4 a = *(const float4*)&sHn[r * 64 + khP * 32 + q * 4];
                    acc[r] += w.x * a.x + w.y * a.y + w.z * a.z + w.w * a.w;
                }
            }
#pragma unroll
            for (int r = 0; r < RPB; ++r) sU[khP * 4112 + r * PP + npP] = acc[r];
        }
        if (hasExtra) {
            float acc[RPB];
#pragma unroll
            for (int r = 0; r < RPB; ++r) acc[r] = 0.f;
#pragma unroll
            for (int q = 0; q < 8; ++q) {
                float4 w = Wq2[q];
#pragma unroll
                for (int r = 0; r < RPB; ++r) {
                    float4 a = *(const float4*)&sHn[r * 64 + 32 + q * 4];
                    acc[r] += w.x * a.x + w.y * a.y + w.z * a.z + w.w * a.w;
                }
            }
#pragma unroll
            for (int r = 0; r < RPB; ++r) sU[4112 + r * PP + npE] = acc[r];
        }
        __syncthreads();
        // ---- phase 4: NTM addressing, one wave per row ----
        if (tid < 512) {
            int row = tid >> 6, lane = tid & 63;
            const int pb = row * PP;
#define PV(n) (sU[pb + (n)] + sU[4112 + pb + (n)] + sBp[(n)])
            float kr1 = tanhf(PV(lane)),       kr2 = tanhf(PV(64 + lane));
            float beta_r = softplusf(PV(128));
            float kw1 = tanhf(PV(129 + lane)), kw2 = tanhf(PV(193 + lane));
            float beta_w = softplusf(PV(257));
            float er1 = sigmf(PV(258 + lane)), er2 = sigmf(PV(322 + lane));
            float ad1 = tanhf(PV(386 + lane)), ad2 = tanhf(PV(450 + lane));
#undef PV
            float M1[4], M2[4];
#pragma unroll
            for (int s = 0; s < 4; ++s) {
                M1[s] = sM[row * 512 + s * 128 + lane];
                M2[s] = sM[row * 512 + s * 128 + 64 + lane];
            }
            float nkr = sqrtf(wred64(kr1 * kr1 + kr2 * kr2)) + 1e-8f;
            float nkw = sqrtf(wred64(kw1 * kw1 + kw2 * kw2)) + 1e-8f;
            float Kr[4], Kw[4];
#pragma unroll
            for (int s = 0; s < 4; ++s) {
                float nM = sqrtf(wred64(M1[s] * M1[s] + M2[s] * M2[s])) + 1e-8f;
                float dr = wred64(kr1 * M1[s] + kr2 * M2[s]);
                float dw = wred64(kw1 * M1[s] + kw2 * M2[s]);
                Kr[s] = dr / (nkr * nM);
                Kw[s] = dw / (nkw * nM);
            }
            float wr_[4], ww_[4];
            {
                float mx = fmaxf(fmaxf(beta_r * Kr[0], beta_r * Kr[1]),
                                 fmaxf(beta_r * Kr[2], beta_r * Kr[3]));
                float sum = 0.f;
#pragma unroll
                for (int s = 0; s < 4; ++s) { wr_[s] = expf(beta_r * Kr[s] - mx); sum += wr_[s]; }
                float inv = 1.f / sum;
#pragma unroll
                for (int s = 0; s < 4; ++s) wr_[s] *= inv;
            }
            {
                float mx = fmaxf(fmaxf(beta_w * Kw[0], beta_w * Kw[1]),
                                 fmaxf(beta_w * Kw[2], beta_w * Kw[3]));
                float sum = 0.f;
#pragma unroll
                for (int s = 0; s < 4; ++s) { ww_[s] = expf(beta_w * Kw[s] - mx); sum += ww_[s]; }
                float inv = 1.f / sum;
#pragma unroll
                for (int s = 0; s < 4; ++s) ww_[s] *= inv;
            }
            float rn1 = 0.f, rn2 = 0.f;
#pragma unroll
            for (int s = 0; s < 4; ++s) { rn1 += wr_[s] * M1[s]; rn2 += wr_[s] * M2[s]; }
            float mt = sMask[row * TT + t];
            bool vld = mt > 0.f;
            if (vld) {
#pragma unroll
                for (int s = 0; s < 4; ++s) {
                    sM[row * 512 + s * 128 + lane]      = M1[s] * (1.f - ww_[s] * er1) + ww_[s] * ad1;
                    sM[row * 512 + s * 128 + 64 + lane] = M2[s] * (1.f - ww_[s] * er2) + ww_[s] * ad2;
                }
                sRd[row * 128 + lane]      = rn1;
                sRd[row * 128 + 64 + lane] = rn2;
            }
            if (t == ts) {
                sU[pb + lane] = rn1; sU[pb + 64 + lane] = rn2;
                __asm__ volatile("s_waitcnt lgkmcnt(0)" ::: "memory");
                float acc = bo[lane];
                const float* wo = Wo + lane * GG;
                for (int k = 0; k < 64; ++k)  acc += sHn[row * 64 + k] * wo[k];
                for (int k = 0; k < 128; ++k) acc += sU[pb + k] * wo[64 + k];
                if (!vld) acc = 0.f;
                last_out[(size_t)(b0 + row) * 64 + lane] = acc;
            }
        }
        __syncthreads();
    }
}

// ---------------- K3: final MLP head --------------------------------------------
__global__ __launch_bounds__(128) void final_mlp(
    const int* __restrict__ item, const int* __restrict__ cate,
    const float* __restrict__ emb,
    const float* __restrict__ hist_sum, const float* __restrict__ last_out,
    const float* __restrict__ fc1w, const float* __restrict__ fc1b,
    const float* __restrict__ pa1,
    const float* __restrict__ fc2w, const float* __restrict__ fc2b,
    const float* __restrict__ pa2,
    const float* __restrict__ fc3w, const float* __restrict__ fc3b,
    float* __restrict__ out)
{
    __shared__ float sX[320], sH1[200], sH2[80];
    int b = blockIdx.x, tid = threadIdx.x;
    int it = item[b], ct = cate[b];
    for (int i = tid; i < 320; i += 128) {
        float val;
        if (i < 64)       val = emb[(size_t)it * 64 + i];
        else if (i < 128) val = emb[(size_t)ct * 64 + (i - 64)];
        else if (i < 256) val = hist_sum[(size_t)b * 128 + (i - 128)];
        else              val = last_out[(size_t)b * 64 + (i - 256)];
        sX[i] = val;
    }
    __syncthreads();
    float a1 = pa1[0];
    for (int o = tid; o < 200; o += 128) {
        const float4* w = (const float4*)(fc1w + o * 320);
        float acc = fc1b[o];
#pragma unroll
        for (int q = 0; q < 80; ++q) {
            float4 ww = w[q];
            const float4 x4 = *(const float4*)&sX[q * 4];
            acc += ww.x * x4.x + ww.y * x4.y + ww.z * x4.z + ww.w * x4.w;
        }
        sH1[o] = acc > 0.f ? acc : a1 * acc;
    }
    __syncthreads();
    float a2 = pa2[0];
    for (int o = tid; o < 80; o += 128) {
        const float4* w = (const float4*)(fc2w + o * 200);
        float acc = fc2b[o];
#pragma unroll
        for (int q = 0; q < 50; ++q) {
            float4 ww = w[q];
            const float4 x4 = *(const float4*)&sH1[q * 4];
            acc += ww.x * x4.x + ww.y * x4.y + ww.z * x4.z + ww.w * x4.w;
        }
        sH2[o] = acc > 0.f ? acc : a2 * acc;
    }
    __syncthreads();
    if (tid < 2) {
        const float4* w = (const float4*)(fc3w + tid * 80);
        float acc = fc3b[tid];
#pragma unroll
        for (int q = 0; q < 20; ++q) {
            float4 ww = w[q];
            const float4 x4 = *(const float4*)&sH2[q * 4];
            acc += ww.x * x4.x + ww.y * x4.y + ww.z * x4.z + ww.w * x4.w;
        }
        out[b * 2 + tid] = acc;
    }
}

extern "C" void kernel_launch(void* const* d_in, const int* in_sizes, int n_in,
                              void* d_out, int out_size, void* d_ws, size_t ws_size,
                              hipStream_t stream) {
    (void)in_sizes; (void)n_in; (void)out_size; (void)ws_size;
    const int*   item      = (const int*)d_in[0];
    const int*   cate      = (const int*)d_in[1];
    const int*   hist_item = (const int*)d_in[2];
    const int*   hist_cate = (const int*)d_in[3];
    const float* mask = (const float*)d_in[4];
    const float* emb  = (const float*)d_in[5];
    const float* Wih  = (const float*)d_in[6];
    const float* Whh  = (const float*)d_in[7];
    const float* bih  = (const float*)d_in[8];
    const float* bhh  = (const float*)d_in[9];
    const float* Wp   = (const float*)d_in[10];
    const float* bp   = (const float*)d_in[11];
    const float* Wo   = (const float*)d_in[12];
    const float* bo   = (const float*)d_in[13];
    const float* M0   = (const float*)d_in[14];
    const float* fc1w = (const float*)d_in[15];
    const float* fc1b = (const float*)d_in[16];
    const float* pa1  = (const float*)d_in[17];
    const float* fc2w = (const float*)d_in[18];
    const float* fc2b = (const float*)d_in[19];
    const float* pa2  = (const float*)d_in[20];
    const float* fc3w = (const float*)d_in[21];
    const float* fc3b = (const float*)d_in[22];

    float* GIi = (float*)d_ws;                                   // V*192 f32
    float* GIc = GIi + (size_t)VV * GG;                          // V*192 f32
    float* hist_sum = GIc + (size_t)VV * GG;                     // B*128 f32
    float* last_out = hist_sum + (size_t)BB * 128;               // B*64 f32
    int* seqlen = (int*)(last_out + (size_t)BB * 64);            // B int

    build_tables<<<(VV + 63) / 64, 192, 0, stream>>>(emb, Wih, bih, GIi, GIc);
    hist_stats<<<BB, 128, 0, stream>>>(hist_item, hist_cate, mask, emb, hist_sum, seqlen);
    mimn_rnn<<<BB / RPB, 1024, 0, stream>>>(hist_item, hist_cate, mask, Wih, Whh, bhh,
                                            Wp, bp, Wo, bo, M0, GIi, GIc, seqlen, last_out);
    final_mlp<<<BB, 128, 0, stream>>>(item, cate, emb, hist_sum, last_out,
                                      fc1w, fc1b, pa1, fc2w, fc2b, pa2, fc3w, fc3b,
                                      (float*)d_out);
}

// Round 6
// 4080.964 us; speedup vs baseline: 3.1761x; 3.1761x over previous
//
#include <hip/hip_runtime.h>

#define VV 100000
#define BB 2048
#define TT 200
#define GG 192   // 3*C
#define PP 514
#define RPB 8    // batch rows per block (mimn_rnn)

__device__ __forceinline__ float sigmf(float x) { return 1.0f / (1.0f + expf(-x)); }
__device__ __forceinline__ float softplusf(float x) {
    return fmaxf(x, 0.0f) + log1pf(expf(-fabsf(x)));
}
__device__ __forceinline__ float wred64(float x) {
#pragma unroll
    for (int m = 32; m >= 1; m >>= 1) x += __shfl_xor(x, m, 64);
    return x;
}
__device__ __forceinline__ float dot4(float4 w, float4 a) {
    return w.x * a.x + w.y * a.y + w.z * a.z + w.w * a.w;
}

// ---------------- K0: per-vocab GI tables (bih folded into GI_item) -------------
__global__ __launch_bounds__(192) void build_tables(
    const float* __restrict__ emb,   // V x 64
    const float* __restrict__ Wih,   // 192 x 256
    const float* __restrict__ bih,   // 192
    float* __restrict__ GIi, float* __restrict__ GIc)  // V x 192 each
{
    __shared__ float sE[64 * 64];
    int tid = threadIdx.x;           // = n
    int v0 = blockIdx.x * 64;
    for (int i = tid; i < 64 * 64; i += 192) {
        int vv = i >> 6, k = i & 63;
        int gv = v0 + vv;
        sE[i] = (gv < VV) ? emb[(size_t)gv * 64 + k] : 0.0f;
    }
    __syncthreads();
    int n = tid;
    float bi = bih[n];
    {
        float4 w[16];
        const float4* wp = (const float4*)(Wih + n * 256);
#pragma unroll
        for (int q = 0; q < 16; ++q) w[q] = wp[q];
        for (int vv = 0; vv < 64; ++vv) {
            int gv = v0 + vv;
            if (gv >= VV) break;
            const float4* e = (const float4*)&sE[vv * 64];
            float acc = bi;
#pragma unroll
            for (int q = 0; q < 16; ++q) acc += dot4(w[q], e[q]);
            GIi[(size_t)gv * GG + n] = acc;
        }
    }
    {
        float4 w[16];
        const float4* wp = (const float4*)(Wih + n * 256 + 64);
#pragma unroll
        for (int q = 0; q < 16; ++q) w[q] = wp[q];
        for (int vv = 0; vv < 64; ++vv) {
            int gv = v0 + vv;
            if (gv >= VV) break;
            const float4* e = (const float4*)&sE[vv * 64];
            float acc = 0.0f;
#pragma unroll
            for (int q = 0; q < 16; ++q) acc += dot4(w[q], e[q]);
            GIc[(size_t)gv * GG + n] = acc;
        }
    }
}

// ---------------- K1: hist_sum + seq_len ----------------------------------------
__global__ __launch_bounds__(128) void hist_stats(
    const int* __restrict__ hist_item, const int* __restrict__ hist_cate,
    const float* __restrict__ mask, const float* __restrict__ emb,
    float* __restrict__ hist_sum, int* __restrict__ seqlen)
{
    int b = blockIdx.x, tid = threadIdx.x;
    const int* hidx = (tid < 64) ? hist_item : hist_cate;   // wave-uniform
    int j = tid & 63;
    float acc = 0.f;
    for (int t = 0; t < TT; ++t) {
        float m = mask[b * TT + t];
        int idx = hidx[b * TT + t];
        acc += m * emb[(size_t)idx * 64 + j];
    }
    hist_sum[(size_t)b * 128 + tid] = acc;
    if (tid < 64) {
        float s = 0.f;
        for (int t = tid; t < TT; t += 64) s += mask[b * TT + t];
        s = wred64(s);
        if (tid == 0) seqlen[b] = (int)(s + 0.5f);
    }
}

// ---------------- K2: recurrence, 512 thr, RPB=8, register-stationary -----------
// Phase-1 roles (wave-aligned):
//   A [0,256):   r,z rows n0=4*(tid&31), fused 192 cols, slice s=tid>>5 (24 cols)
//                W[24] = 4n x 6 float4
//   B [256,384): i_n rows n0=128+4*(u&15), read cols, slice s=u>>4 (16 cols)
//                W[16] = 4n x 4 float4
//   C [384,448): h_n rows n0=128+4*(u&15), h cols, slice s=u>>4 of 4 (16 cols)
//                W[16] = 4n x 4 float4
//   D [448,512): gather: g=tid-448, r=g>>3, n0=24*(g&7); W[0..5]=GIi f4,
//                W[6..11]=GIc f4 (prefetched one step ahead)
// Phase 3 (all): Wq[16] = Wp rows 4*(tid&127).. x cols 16*(tid>>7)..; tail rows
//                512/513 from sWpTail by tids 448..451.
__global__ __launch_bounds__(512, 1) void mimn_rnn(
    const int* __restrict__ hist_item, const int* __restrict__ hist_cate,
    const float* __restrict__ mask,
    const float* __restrict__ Wih,   // 192x256 (cols 128..255 = read part)
    const float* __restrict__ Whh,   // 192x64
    const float* __restrict__ bhh,   // 192
    const float* __restrict__ Wp,    // 514x64
    const float* __restrict__ bp,    // 514
    const float* __restrict__ Wo,    // 64x192
    const float* __restrict__ bo,    // 64
    const float* __restrict__ M0,    // 4x128
    const float* __restrict__ GIi, const float* __restrict__ GIc,
    const int* __restrict__ seqlen,
    float* __restrict__ last_out)    // B x 64
{
    // sU union:
    //  ph1/2: A-partials [s*1024 + r*128 + n] (8192) | i_n 8192+[s*512+r*64+n2]
    //         (4096) | h_n 12288+[s*512+r*64+n2] (2048)
    //  ph3/4: p partials [s*4160 + r*520 + n] (4 slices x 8 r x 520)
    __shared__ __align__(16) float sU[16640];
    __shared__ __align__(16) float sGI[RPB * 192];   // committed gather (step t)
    __shared__ __align__(16) float sAct[RPB * 192];  // [0,128)=read, [128,192)=h (committed)
    __shared__ __align__(16) float sHn[RPB * 64];    // unmasked h_new
    __shared__ float sM [RPB * 512];
    __shared__ float sBp[PP];
    __shared__ float sBhh[GG];
    __shared__ __align__(16) float sWpTail[2 * 64];  // Wp rows 512,513
    __shared__ float sMask[RPB * TT];
    __shared__ int   sHI[RPB * TT];
    __shared__ int   sHC[RPB * TT];

    const int tid = threadIdx.x;
    const int b0 = blockIdx.x * RPB;
    const int r8 = tid >> 6, lane = tid & 63;        // wave id = batch row in ph2/4

    // ---- init staged state ----
    for (int i = tid; i < RPB * 192; i += 512) { sAct[i] = 0.f; sGI[i] = 0.f; }
    for (int i = tid; i < RPB * 64; i += 512) sHn[i] = 0.f;
    for (int i = tid; i < RPB * 512; i += 512) sM[i] = M0[i & 511];
    for (int i = tid; i < PP; i += 512) sBp[i] = bp[i];
    if (tid < GG) sBhh[tid] = bhh[tid];
    if (tid < 128) sWpTail[tid] = Wp[512 * 64 + tid];
    for (int i = tid; i < RPB * TT; i += 512) {
        int r = i / TT, tt = i - r * TT;
        sMask[i] = mask[(size_t)(b0 + r) * TT + tt];
        sHI[i]   = hist_item[(size_t)(b0 + r) * TT + tt];
        sHC[i]   = hist_cate[(size_t)(b0 + r) * TT + tt];
    }

    // ---- hoist weights (single W/Wq arrays: uniform register liveness) ----
    float4 W[24];
    float4 Wq[16];
    int roleNg = 0, roleS = 0;
    if (tid < 256) {                      // A
        roleNg = tid & 31; roleS = tid >> 5;
        int n0 = 4 * roleNg, c0 = 24 * roleS;
#pragma unroll
        for (int ni = 0; ni < 4; ++ni)
#pragma unroll
            for (int jc = 0; jc < 6; ++jc) {
                int c = c0 + 4 * jc;
                W[ni * 6 + jc] = (c < 128)
                    ? *(const float4*)(Wih + (n0 + ni) * 256 + 128 + c)
                    : *(const float4*)(Whh + (n0 + ni) * 64 + (c - 128));
            }
    } else if (tid < 384) {               // B
        int u = tid - 256; roleNg = u & 15; roleS = u >> 4;
        int n0 = 128 + 4 * roleNg, c0 = 16 * roleS;
#pragma unroll
        for (int ni = 0; ni < 4; ++ni)
#pragma unroll
            for (int jc = 0; jc < 4; ++jc)
                W[ni * 4 + jc] = *(const float4*)(Wih + (n0 + ni) * 256 + 128 + c0 + 4 * jc);
    } else if (tid < 448) {               // C
        int u = tid - 384; roleNg = u & 15; roleS = u >> 4;
        int n0 = 128 + 4 * roleNg, c0 = 16 * roleS;
#pragma unroll
        for (int ni = 0; ni < 4; ++ni)
#pragma unroll
            for (int jc = 0; jc < 4; ++jc)
                W[ni * 4 + jc] = *(const float4*)(Whh + (n0 + ni) * 64 + c0 + 4 * jc);
    } else {                              // D
        roleNg = tid - 448;
    }
    {   // Wp slice (all threads)
        int ngP = tid & 127, sP = tid >> 7;
        int n0 = 4 * ngP, c0 = 16 * sP;
#pragma unroll
        for (int ni = 0; ni < 4; ++ni)
#pragma unroll
            for (int jc = 0; jc < 4; ++jc)
                Wq[ni * 4 + jc] = *(const float4*)(Wp + (n0 + ni) * 64 + c0 + 4 * jc);
    }
    int ts = seqlen[b0 + r8] - 1;
    ts = ts < 0 ? 0 : (ts > TT - 1 ? TT - 1 : ts);
    __syncthreads();

    // ---- initial gather prefetch (t = 0) ----
    if (tid >= 448) {
        int rD = roleNg >> 3, n0D = (roleNg & 7) * 24;
        int ri = sHI[rD * TT], rc = sHC[rD * TT];
#pragma unroll
        for (int k = 0; k < 6; ++k) {
            W[k]     = *(const float4*)(GIi + (size_t)ri * GG + n0D + 4 * k);
            W[6 + k] = *(const float4*)(GIc + (size_t)rc * GG + n0D + 4 * k);
        }
    }

    for (int t = 0; t < TT; ++t) {
        // ---- phase 1 ----
        if (tid < 256) {                  // A: fused r,z
            int c0 = 24 * roleS;
            float acc[4][8];
#pragma unroll
            for (int ni = 0; ni < 4; ++ni)
#pragma unroll
                for (int r = 0; r < 8; ++r) acc[ni][r] = 0.f;
#pragma unroll
            for (int jc = 0; jc < 6; ++jc) {
#pragma unroll
                for (int r = 0; r < 8; ++r) {
                    float4 a = *(const float4*)&sAct[r * 192 + c0 + 4 * jc];
#pragma unroll
                    for (int ni = 0; ni < 4; ++ni) acc[ni][r] += dot4(W[ni * 6 + jc], a);
                }
            }
#pragma unroll
            for (int r = 0; r < 8; ++r)
                *(float4*)&sU[roleS * 1024 + r * 128 + 4 * roleNg] =
                    make_float4(acc[0][r], acc[1][r], acc[2][r], acc[3][r]);
        } else if (tid < 384) {           // B: i_n (read cols)
            int c0 = 16 * roleS;
            float acc[4][8];
#pragma unroll
            for (int ni = 0; ni < 4; ++ni)
#pragma unroll
                for (int r = 0; r < 8; ++r) acc[ni][r] = 0.f;
#pragma unroll
            for (int jc = 0; jc < 4; ++jc) {
#pragma unroll
                for (int r = 0; r < 8; ++r) {
                    float4 a = *(const float4*)&sAct[r * 192 + c0 + 4 * jc];
#pragma unroll
                    for (int ni = 0; ni < 4; ++ni) acc[ni][r] += dot4(W[ni * 4 + jc], a);
                }
            }
#pragma unroll
            for (int r = 0; r < 8; ++r)
                *(float4*)&sU[8192 + roleS * 512 + r * 64 + 4 * roleNg] =
                    make_float4(acc[0][r], acc[1][r], acc[2][r], acc[3][r]);
        } else if (tid < 448) {           // C: h_n (h cols)
            int c0 = 128 + 16 * roleS;
            float acc[4][8];
#pragma unroll
            for (int ni = 0; ni < 4; ++ni)
#pragma unroll
                for (int r = 0; r < 8; ++r) acc[ni][r] = 0.f;
#pragma unroll
            for (int jc = 0; jc < 4; ++jc) {
#pragma unroll
                for (int r = 0; r < 8; ++r) {
                    float4 a = *(const float4*)&sAct[r * 192 + c0 + 4 * jc];
#pragma unroll
                    for (int ni = 0; ni < 4; ++ni) acc[ni][r] += dot4(W[ni * 4 + jc], a);
                }
            }
#pragma unroll
            for (int r = 0; r < 8; ++r)
                *(float4*)&sU[12288 + roleS * 512 + r * 64 + 4 * roleNg] =
                    make_float4(acc[0][r], acc[1][r], acc[2][r], acc[3][r]);
        } else {                          // D: commit gather, prefetch t+1
            int rD = roleNg >> 3, n0D = (roleNg & 7) * 24;
#pragma unroll
            for (int k = 0; k < 6; ++k) {
                float4 gi = W[k], gc = W[6 + k];
                *(float4*)&sGI[rD * 192 + n0D + 4 * k] =
                    make_float4(gi.x + gc.x, gi.y + gc.y, gi.z + gc.z, gi.w + gc.w);
            }
            int tn = (t + 1 < TT) ? t + 1 : TT - 1;
            int ri = sHI[rD * TT + tn], rc = sHC[rD * TT + tn];
#pragma unroll
            for (int k = 0; k < 6; ++k) {
                W[k]     = *(const float4*)(GIi + (size_t)ri * GG + n0D + 4 * k);
                W[6 + k] = *(const float4*)(GIc + (size_t)rc * GG + n0D + 4 * k);
            }
        }
        __syncthreads();
        // ---- phase 2: GRU gates; commit h ----
        {
            int r = r8;
            float g_r = sBhh[lane] + sGI[r * 192 + lane];
            float g_z = sBhh[64 + lane] + sGI[r * 192 + 64 + lane];
#pragma unroll
            for (int s = 0; s < 8; ++s) {
                g_r += sU[s * 1024 + r * 128 + lane];
                g_z += sU[s * 1024 + r * 128 + 64 + lane];
            }
            float i_n = sGI[r * 192 + 128 + lane];
#pragma unroll
            for (int s = 0; s < 8; ++s) i_n += sU[8192 + s * 512 + r * 64 + lane];
            float h_n = sBhh[128 + lane];
#pragma unroll
            for (int s = 0; s < 4; ++s) h_n += sU[12288 + s * 512 + r * 64 + lane];
            float rg = sigmf(g_r);
            float zg = sigmf(g_z);
            float ng = tanhf(i_n + rg * h_n);
            float h_old = sAct[r * 192 + 128 + lane];
            float hn = (1.f - zg) * ng + zg * h_old;
            float mt = sMask[r * TT + t];
            sHn[r * 64 + lane] = hn;
            sAct[r * 192 + 128 + lane] = (mt > 0.f) ? hn : h_old;
        }
        __syncthreads();
        // ---- phase 3: p partials = h_new @ Wp^T ----
        {
            int ngP = tid & 127, sP = tid >> 7;
            int n0 = 4 * ngP, c0 = 16 * sP;
            float acc[4][8];
#pragma unroll
            for (int ni = 0; ni < 4; ++ni)
#pragma unroll
                for (int r = 0; r < 8; ++r) acc[ni][r] = 0.f;
#pragma unroll
            for (int jc = 0; jc < 4; ++jc) {
#pragma unroll
                for (int r = 0; r < 8; ++r) {
                    float4 a = *(const float4*)&sHn[r * 64 + c0 + 4 * jc];
#pragma unroll
                    for (int ni = 0; ni < 4; ++ni) acc[ni][r] += dot4(Wq[ni * 4 + jc], a);
                }
            }
#pragma unroll
            for (int r = 0; r < 8; ++r)
                *(float4*)&sU[sP * 4160 + r * 520 + n0] =
                    make_float4(acc[0][r], acc[1][r], acc[2][r], acc[3][r]);
        }
        if (tid >= 448 && tid < 452) {    // tail Wp rows 512,513 (from LDS copy)
            int s2 = tid - 448, c0 = 16 * s2;
            float a0[8], a1[8];
#pragma unroll
            for (int r = 0; r < 8; ++r) { a0[r] = 0.f; a1[r] = 0.f; }
#pragma unroll
            for (int jc = 0; jc < 4; ++jc) {
                float4 w0 = *(const float4*)&sWpTail[c0 + 4 * jc];
                float4 w1 = *(const float4*)&sWpTail[64 + c0 + 4 * jc];
#pragma unroll
                for (int r = 0; r < 8; ++r) {
                    float4 a = *(const float4*)&sHn[r * 64 + c0 + 4 * jc];
                    a0[r] += dot4(w0, a);
                    a1[r] += dot4(w1, a);
                }
            }
#pragma unroll
            for (int r = 0; r < 8; ++r)
                *(float2*)&sU[s2 * 4160 + r * 520 + 512] = make_float2(a0[r], a1[r]);
        }
        __syncthreads();
        // ---- phase 4: NTM addressing, one wave per row ----
        {
            int row = r8;
            const int pb = row * 520;
#define PV(n) (sU[pb + (n)] + sU[4160 + pb + (n)] + sU[8320 + pb + (n)] + sU[12480 + pb + (n)] + sBp[(n)])
            float kr1 = tanhf(PV(lane)),       kr2 = tanhf(PV(64 + lane));
            float beta_r = softplusf(PV(128));
            float kw1 = tanhf(PV(129 + lane)), kw2 = tanhf(PV(193 + lane));
            float beta_w = softplusf(PV(257));
            float er1 = sigmf(PV(258 + lane)), er2 = sigmf(PV(322 + lane));
            float ad1 = tanhf(PV(386 + lane)), ad2 = tanhf(PV(450 + lane));
#undef PV
            float M1[4], M2[4];
#pragma unroll
            for (int s = 0; s < 4; ++s) {
                M1[s] = sM[row * 512 + s * 128 + lane];
                M2[s] = sM[row * 512 + s * 128 + 64 + lane];
            }
            float nkr = sqrtf(wred64(kr1 * kr1 + kr2 * kr2)) + 1e-8f;
            float nkw = sqrtf(wred64(kw1 * kw1 + kw2 * kw2)) + 1e-8f;
            float Kr[4], Kw[4];
#pragma unroll
            for (int s = 0; s < 4; ++s) {
                float nM = sqrtf(wred64(M1[s] * M1[s] + M2[s] * M2[s])) + 1e-8f;
                float dr = wred64(kr1 * M1[s] + kr2 * M2[s]);
                float dw = wred64(kw1 * M1[s] + kw2 * M2[s]);
                Kr[s] = dr / (nkr * nM);
                Kw[s] = dw / (nkw * nM);
            }
            float wr_[4], ww_[4];
            {
                float mx = fmaxf(fmaxf(beta_r * Kr[0], beta_r * Kr[1]),
                                 fmaxf(beta_r * Kr[2], beta_r * Kr[3]));
                float sum = 0.f;
#pragma unroll
                for (int s = 0; s < 4; ++s) { wr_[s] = expf(beta_r * Kr[s] - mx); sum += wr_[s]; }
                float inv = 1.f / sum;
#pragma unroll
                for (int s = 0; s < 4; ++s) wr_[s] *= inv;
            }
            {
                float mx = fmaxf(fmaxf(beta_w * Kw[0], beta_w * Kw[1]),
                                 fmaxf(beta_w * Kw[2], beta_w * Kw[3]));
                float sum = 0.f;
#pragma unroll
                for (int s = 0; s < 4; ++s) { ww_[s] = expf(beta_w * Kw[s] - mx); sum += ww_[s]; }
                float inv = 1.f / sum;
#pragma unroll
                for (int s = 0; s < 4; ++s) ww_[s] *= inv;
            }
            float rn1 = 0.f, rn2 = 0.f;
#pragma unroll
            for (int s = 0; s < 4; ++s) { rn1 += wr_[s] * M1[s]; rn2 += wr_[s] * M2[s]; }
            float mt = sMask[row * TT + t];
            bool vld = mt > 0.f;
            if (vld) {
#pragma unroll
                for (int s = 0; s < 4; ++s) {
                    sM[row * 512 + s * 128 + lane]      = M1[s] * (1.f - ww_[s] * er1) + ww_[s] * ad1;
                    sM[row * 512 + s * 128 + 64 + lane] = M2[s] * (1.f - ww_[s] * er2) + ww_[s] * ad2;
                }
                sAct[row * 192 + lane]      = rn1;   // committed read
                sAct[row * 192 + 64 + lane] = rn2;
            }
            if (t == ts) {
                // out = [h_new, read_new] @ Wo^T + bo  (unmasked values)
                sGI[row * 192 + lane] = rn1; sGI[row * 192 + 64 + lane] = rn2;
                __asm__ volatile("s_waitcnt lgkmcnt(0)" ::: "memory");
                float acc = bo[lane];
                const float* wo = Wo + lane * GG;
                for (int k = 0; k < 64; ++k)  acc += sHn[row * 64 + k] * wo[k];
                for (int k = 0; k < 128; ++k) acc += sGI[row * 192 + k] * wo[64 + k];
                if (!vld) acc = 0.f;
                last_out[(size_t)(b0 + row) * 64 + lane] = acc;
            }
        }
        __syncthreads();
    }
}

// ---------------- K3: final MLP head --------------------------------------------
__global__ __launch_bounds__(128) void final_mlp(
    const int* __restrict__ item, const int* __restrict__ cate,
    const float* __restrict__ emb,
    const float* __restrict__ hist_sum, const float* __restrict__ last_out,
    const float* __restrict__ fc1w, const float* __restrict__ fc1b,
    const float* __restrict__ pa1,
    const float* __restrict__ fc2w, const float* __restrict__ fc2b,
    const float* __restrict__ pa2,
    const float* __restrict__ fc3w, const float* __restrict__ fc3b,
    float* __restrict__ out)
{
    __shared__ float sX[320], sH1[200], sH2[80];
    int b = blockIdx.x, tid = threadIdx.x;
    int it = item[b], ct = cate[b];
    for (int i = tid; i < 320; i += 128) {
        float val;
        if (i < 64)       val = emb[(size_t)it * 64 + i];
        else if (i < 128) val = emb[(size_t)ct * 64 + (i - 64)];
        else if (i < 256) val = hist_sum[(size_t)b * 128 + (i - 128)];
        else              val = last_out[(size_t)b * 64 + (i - 256)];
        sX[i] = val;
    }
    __syncthreads();
    float a1 = pa1[0];
    for (int o = tid; o < 200; o += 128) {
        const float4* w = (const float4*)(fc1w + o * 320);
        float acc = fc1b[o];
#pragma unroll
        for (int q = 0; q < 80; ++q) acc += dot4(w[q], *(const float4*)&sX[q * 4]);
        sH1[o] = acc > 0.f ? acc : a1 * acc;
    }
    __syncthreads();
    float a2 = pa2[0];
    for (int o = tid; o < 80; o += 128) {
        const float4* w = (const float4*)(fc2w + o * 200);
        float acc = fc2b[o];
#pragma unroll
        for (int q = 0; q < 50; ++q) acc += dot4(w[q], *(const float4*)&sH1[q * 4]);
        sH2[o] = acc > 0.f ? acc : a2 * acc;
    }
    __syncthreads();
    if (tid < 2) {
        const float4* w = (const float4*)(fc3w + tid * 80);
        float acc = fc3b[tid];
#pragma unroll
        for (int q = 0; q < 20; ++q) acc += dot4(w[q], *(const float4*)&sH2[q * 4]);
        out[b * 2 + tid] = acc;
    }
}

extern "C" void kernel_launch(void* const* d_in, const int* in_sizes, int n_in,
                              void* d_out, int out_size, void* d_ws, size_t ws_size,
                              hipStream_t stream) {
    (void)in_sizes; (void)n_in; (void)out_size; (void)ws_size;
    const int*   item      = (const int*)d_in[0];
    const int*   cate      = (const int*)d_in[1];
    const int*   hist_item = (const int*)d_in[2];
    const int*   hist_cate = (const int*)d_in[3];
    const float* mask = (const float*)d_in[4];
    const float* emb  = (const float*)d_in[5];
    const float* Wih  = (const float*)d_in[6];
    const float* Whh  = (const float*)d_in[7];
    const float* bih  = (const float*)d_in[8];
    const float* bhh  = (const float*)d_in[9];
    const float* Wp   = (const float*)d_in[10];
    const float* bp   = (const float*)d_in[11];
    const float* Wo   = (const float*)d_in[12];
    const float* bo   = (const float*)d_in[13];
    const float* M0   = (const float*)d_in[14];
    const float* fc1w = (const float*)d_in[15];
    const float* fc1b = (const float*)d_in[16];
    const float* pa1  = (const float*)d_in[17];
    const float* fc2w = (const float*)d_in[18];
    const float* fc2b = (const float*)d_in[19];
    const float* pa2  = (const float*)d_in[20];
    const float* fc3w = (const float*)d_in[21];
    const float* fc3b = (const float*)d_in[22];

    float* GIi = (float*)d_ws;                                   // V*192 f32
    float* GIc = GIi + (size_t)VV * GG;                          // V*192 f32
    float* hist_sum = GIc + (size_t)VV * GG;                     // B*128 f32
    float* last_out = hist_sum + (size_t)BB * 128;               // B*64 f32
    int* seqlen = (int*)(last_out + (size_t)BB * 64);            // B int

    build_tables<<<(VV + 63) / 64, 192, 0, stream>>>(emb, Wih, bih, GIi, GIc);
    hist_stats<<<BB, 128, 0, stream>>>(hist_item, hist_cate, mask, emb, hist_sum, seqlen);
    mimn_rnn<<<BB / RPB, 512, 0, stream>>>(hist_item, hist_cate, mask, Wih, Whh, bhh,
                                           Wp, bp, Wo, bo, M0, GIi, GIc, seqlen, last_out);
    final_mlp<<<BB, 128, 0, stream>>>(item, cate, emb, hist_sum, last_out,
                                      fc1w, fc1b, pa1, fc2w, fc2b, pa2, fc3w, fc3b,
                                      (float*)d_out);
}